// Round 13
// baseline (413.857 us; speedup 1.0000x reference)
//
#include <hip/hip_runtime.h>

typedef __attribute__((ext_vector_type(8))) short bf16x8;
typedef __attribute__((ext_vector_type(4))) float f32x4;

__device__ inline float bf2f(unsigned short u) {
    union { float f; unsigned int i; } v; v.i = ((unsigned int)u) << 16; return v.f;
}
__device__ inline unsigned short f2bf(float f) {
    union { float f; unsigned int u; } v; v.f = f;
    unsigned int x = v.u;
    unsigned int r = x + 0x7FFFu + ((x >> 16) & 1u);
    return (unsigned short)(r >> 16);
}
// order-preserving float <-> uint for atomicMax
__device__ inline unsigned int fenc(float x) {
    union { float f; unsigned int u; } v; v.f = x;
    return (v.u & 0x80000000u) ? ~v.u : (v.u | 0x80000000u);
}
__device__ inline float fdec(unsigned int k) {
    union { float f; unsigned int u; } v;
    v.u = (k & 0x80000000u) ? (k & 0x7FFFFFFFu) : ~k;
    return v.f;
}
// dual-format loads: f32flag ? float32 buffer : bf16 buffer
__device__ inline float ldf(const void* p, size_t i, int f32) {
    return f32 ? ((const float*)p)[i] : bf2f(((const unsigned short*)p)[i]);
}
// i64flag ? int64 buffer (values < 2^31, take low word) : int32 buffer
__device__ inline int ldi(const int* p, size_t i, int i64) {
    return i64 ? p[2 * i] : p[i];
}

// ---------------- zero scratch + format detection (fused; block 0 = detect) ----------------
__global__ void k_init(const unsigned short* __restrict__ xu, int xstride,
                       const int* __restrict__ ei, int estride, int* __restrict__ flags,
                       int* __restrict__ hist, int* __restrict__ cursor,
                       float* __restrict__ psum, unsigned int* __restrict__ pkey,
                       int* __restrict__ pcnt, int N) {
    if (blockIdx.x == 0) {
        __shared__ int cnt, orv;
        if (threadIdx.x == 0) { cnt = 0; orv = 0; }
        __syncthreads();
        int c = 0, o = 0;
        for (int s = 0; s < 4; ++s) {
            int j = threadIdx.x * 4 + s;               // 0..1023
            size_t k = (size_t)j * xstride;            // < xelems/2
            unsigned short u = xu[2 * k];              // even ushort
            int e = (u >> 7) & 0xFF;
            if (e >= 100 && e <= 140) ++c;             // sane bf16 exponent?
            size_t idx = (size_t)j * estride;          // < E
            o |= ei[2 * idx + 1];                      // odd word
        }
        atomicAdd(&cnt, c); atomicOr(&orv, o);
        __syncthreads();
        if (threadIdx.x == 0) {
            flags[0] = (cnt < 768) ? 1 : 0;   // 1 => floats are f32
            flags[1] = (orv == 0) ? 1 : 0;    // 1 => ints are int64
        }
        return;
    }
    int t = (blockIdx.x - 1) * 256 + threadIdx.x;
    if (t < N) hist[t] = 0;
    else if (t < 2 * N) cursor[t - N] = 0;
    else if (t < 2 * N + 16384) psum[t - 2 * N] = 0.f;
    else if (t < 2 * N + 32768) pkey[t - 2 * N - 16384] = 0u;
    else if (t < 2 * N + 32768 + 64) pcnt[t - 2 * N - 32768] = 0;
}

// ---------------- X -> bf16 conversion (or copy if already bf16) ----------------
__global__ __launch_bounds__(256)
void k_cvt(const void* __restrict__ X, unsigned short* __restrict__ Xb,
           size_t nelem, const int* __restrict__ flags) {
    int f = flags[0];
    size_t i = ((size_t)blockIdx.x * 256 + threadIdx.x) * 8;
    if (i >= nelem) return;
    if (f) {
        const float* s = (const float*)X + i;
        float4 f0 = *(const float4*)s;
        float4 f1 = *(const float4*)(s + 4);
        int4 o;
        o.x = (int)f2bf(f0.x) | ((int)f2bf(f0.y) << 16);
        o.y = (int)f2bf(f0.z) | ((int)f2bf(f0.w) << 16);
        o.z = (int)f2bf(f1.x) | ((int)f2bf(f1.y) << 16);
        o.w = (int)f2bf(f1.z) | ((int)f2bf(f1.w) << 16);
        *(int4*)(Xb + i) = o;
    } else {
        *(int4*)(Xb + i) = *(const int4*)((const unsigned short*)X + i);
    }
}

// ---------------- weight convert + transpose ----------------
__global__ __launch_bounds__(256)
void k_cvtw(const void* __restrict__ pre_w, const void* __restrict__ gcn_w,
            unsigned short* __restrict__ Pb, unsigned short* __restrict__ Gt,
            const int* __restrict__ flags) {
    __shared__ float tile[64][65];
    const int i = blockIdx.y;
    const int m0 = (blockIdx.x & 3) * 64;
    const int n0 = (blockIdx.x >> 2) * 64;
    const int f = flags[0];
    const size_t base = (size_t)i * 65536;
#pragma unroll
    for (int q = 0; q < 16; ++q) {
        int idx = q * 256 + threadIdx.x;
        int r = idx >> 6, c = idx & 63;
        size_t src = base + (size_t)(m0 + r) * 256 + n0 + c;
        Pb[src] = f2bf(ldf(pre_w, src, f));
        tile[r][c] = ldf(gcn_w, src, f);
    }
    __syncthreads();
#pragma unroll
    for (int q = 0; q < 16; ++q) {
        int idx = q * 256 + threadIdx.x;
        int r = idx >> 6, c = idx & 63;
        Gt[base + (size_t)(n0 + r) * 256 + m0 + c] = f2bf(tile[c][r]);
    }
}

// ---------------- weight folding via MFMA ----------------
__global__ __launch_bounds__(256)
void k_prepw(const unsigned short* __restrict__ Pb, const unsigned short* __restrict__ Gt,
             unsigned short* __restrict__ Wt0, unsigned short* __restrict__ Wt1) {
    const int which = blockIdx.y;
    const int wid = threadIdx.x >> 6, lane = threadIdx.x & 63;
    const int tile = blockIdx.x * 4 + wid;       // 0..255
    const int n0 = (tile >> 4) * 16, k0 = (tile & 15) * 16;
    const int l15 = lane & 15, hi = lane >> 4;
    size_t base0, base1 = 0;
    if (which == 0)      { base0 = 0; base1 = 65536; }
    else if (which == 1) { base0 = 2 * 65536; }
    else                 { base0 = 3 * 65536; }
    f32x4 acc0 = {}, acc1 = {};
    const unsigned short* ga = Gt + base0 + (size_t)(n0 + l15) * 256 + hi * 8;
    const unsigned short* pa = Pb + base0 + (size_t)(k0 + l15) * 256 + hi * 8;
    const unsigned short* gb = Gt + base1 + (size_t)(n0 + l15) * 256 + hi * 8;
    const unsigned short* pb = Pb + base1 + (size_t)(k0 + l15) * 256 + hi * 8;
#pragma unroll
    for (int kt = 0; kt < 8; ++kt) {
        bf16x8 a0 = *(const bf16x8*)(ga + kt * 32);
        bf16x8 b0 = *(const bf16x8*)(pa + kt * 32);
        acc0 = __builtin_amdgcn_mfma_f32_16x16x32_bf16(a0, b0, acc0, 0, 0, 0);
        if (which == 0) {
            bf16x8 a1 = *(const bf16x8*)(gb + kt * 32);
            bf16x8 b1 = *(const bf16x8*)(pb + kt * 32);
            acc1 = __builtin_amdgcn_mfma_f32_16x16x32_bf16(a1, b1, acc1, 0, 0, 0);
        }
    }
#pragma unroll
    for (int j = 0; j < 4; ++j) {
        int n = n0 + hi * 4 + j;
        int k = k0 + l15;
        if (which == 0)      Wt0[(size_t)n * 256 + k]       = f2bf(2.f * acc0[j] + acc1[j]);
        else if (which == 1) Wt1[(size_t)n * 512 + k]       = f2bf(2.f * acc0[j]);
        else                 Wt1[(size_t)n * 512 + 256 + k] = f2bf(acc0[j]);
    }
}

// ---------------- bias folding (uses Gt: contiguous bf16 rows) ----------------
__global__ __launch_bounds__(256)
void k_prepb(const void* __restrict__ pre_b, const unsigned short* __restrict__ Gt,
             const void* __restrict__ gcn_b,
             float* __restrict__ cvec, float* __restrict__ dvec,
             const int* __restrict__ flags) {
    __shared__ float pb[2][256];
    const int l = blockIdx.x, n = threadIdx.x;
    const int f = flags[0];
    pb[0][n] = ldf(pre_b, (size_t)(l * 2 + 0) * 256 + n, f);
    pb[1][n] = ldf(pre_b, (size_t)(l * 2 + 1) * 256 + n, f);
    __syncthreads();
    const unsigned short* g0 = Gt + (size_t)(l * 2 + 0) * 65536 + (size_t)n * 256;
    const unsigned short* g1 = Gt + (size_t)(l * 2 + 1) * 65536 + (size_t)n * 256;
    float a = 0.f, b = 0.f;
#pragma unroll 4
    for (int mc = 0; mc < 32; ++mc) {
        bf16x8 v0 = *(const bf16x8*)(g0 + mc * 8);
        bf16x8 v1 = *(const bf16x8*)(g1 + mc * 8);
#pragma unroll
        for (int u = 0; u < 8; ++u) {
            a += pb[0][mc * 8 + u] * bf2f((unsigned short)v0[u]);
            b += pb[1][mc * 8 + u] * bf2f((unsigned short)v1[u]);
        }
    }
    cvec[l * 256 + n] = 2.f * a + b;
    dvec[l * 256 + n] = 2.f * ldf(gcn_b, (size_t)(l * 2 + 0) * 256 + n, f)
                            + ldf(gcn_b, (size_t)(l * 2 + 1) * 256 + n, f);
}

// ---------------- CSR build ----------------
__global__ void k_hist(const int* __restrict__ ei, int E, int N,
                       int* __restrict__ hist, const int* __restrict__ flags) {
    int e = blockIdx.x * 256 + threadIdx.x;
    if (e >= E) return;
    int i64 = flags[1];
    int d = ldi(ei, (size_t)E + e, i64); d = d < 0 ? 0 : (d >= N ? N - 1 : d);
    atomicAdd(&hist[d], 1);
}

__global__ __launch_bounds__(256)
void k_scan1(const int* __restrict__ hist, int* __restrict__ pre,
             int* __restrict__ bsum, int N) {
    __shared__ int s[256];
    int i = blockIdx.x * 256 + threadIdx.x;
    int v = (i < N) ? hist[i] : 0;
    s[threadIdx.x] = v;
    __syncthreads();
    for (int off = 1; off < 256; off <<= 1) {
        int t = (threadIdx.x >= off) ? s[threadIdx.x - off] : 0;
        __syncthreads();
        s[threadIdx.x] += t;
        __syncthreads();
    }
    if (i < N) pre[i] = s[threadIdx.x] - v;          // exclusive within block
    if (threadIdx.x == 255) bsum[blockIdx.x] = s[255];
}

__global__ __launch_bounds__(256)
void k_scan2(const int* __restrict__ bsum, int* __restrict__ boff,
             int* __restrict__ rowptr, int nb, int N) {
    __shared__ int s[256];
    int t = threadIdx.x;
    int v = (t < nb) ? bsum[t] : 0;
    s[t] = v;
    __syncthreads();
    for (int off = 1; off < 256; off <<= 1) {
        int x = (t >= off) ? s[t - off] : 0;
        __syncthreads();
        s[t] += x;
        __syncthreads();
    }
    if (t < nb) boff[t] = s[t] - v;                  // exclusive block offset
    if (t == nb - 1) rowptr[N] = s[t];               // grand total
}

__global__ __launch_bounds__(256)
void k_scan3(const int* __restrict__ hist, const int* __restrict__ pre,
             const int* __restrict__ boff, int* __restrict__ rowptr,
             float* __restrict__ dinv, int N) {
    int i = blockIdx.x * 256 + threadIdx.x;
    if (i < N) {
        rowptr[i] = pre[i] + boff[blockIdx.x];
        dinv[i] = rsqrtf((float)(hist[i] + 1));
    }
}

__global__ void k_scatter(const int* __restrict__ ei, int E, int N,
                          const int* __restrict__ rowptr, int* __restrict__ cursor,
                          int* __restrict__ col, const int* __restrict__ flags) {
    int e = blockIdx.x * 256 + threadIdx.x;
    if (e >= E) return;
    int i64 = flags[1];
    int s = ldi(ei, (size_t)e, i64);     s = s < 0 ? 0 : (s >= N ? N - 1 : s);
    int d = ldi(ei, (size_t)E + e, i64); d = d < 0 ? 0 : (d >= N ? N - 1 : d);
    int pos = rowptr[d] + atomicAdd(&cursor[d], 1);
    col[pos] = s;
}

// ---------------- main GEMM: out[i,:] = dinv[i] * (A[i,:] @ W + c) ----------------
// Barrier-free K-loop + 2-deep NAMED-register fragment double-buffer:
// loads of step s+1 issue BEFORE MFMAs of step s; no barrier exists to drain
// vmcnt, so ~16 loads/wave stay in flight (2x R10's MLP). 128x256 tile,
// 512 thr = 8 waves (2x4), wave tile 64x64, acc[4][4]. A rows hit L2 via
// 4-wave sharing; W is L2-resident. LDS only for dense-store epilogue.
__global__ __launch_bounds__(512)
void k_gemm(const unsigned short* __restrict__ Xb, const unsigned short* __restrict__ Yb,
            const unsigned short* __restrict__ Wt, const float* __restrict__ cvec,
            const float* __restrict__ dinv, unsigned short* __restrict__ out,
            int M, int K) {
    __shared__ char ldsb[32768];                 // epilogue tile: 64 rows x 512B
    const int tid = threadIdx.x;
    const int lane = tid & 63;
    const int wid = tid >> 6;                    // 0..7
    const int wm = wid >> 2, wn = wid & 3;       // 2 x 4 waves
    const int l15 = lane & 15, hi = lane >> 4;
    const int row0 = blockIdx.x * 128;

    // fragment base offsets (elements; fit in 32-bit)
    unsigned int aoff[4], woff[4];
#pragma unroll
    for (int m = 0; m < 4; ++m) {
        int r = row0 + wm * 64 + m * 16 + l15;
        if (r > M - 1) r = M - 1;
        aoff[m] = (unsigned int)r * 256u + hi * 8;
    }
#pragma unroll
    for (int n = 0; n < 4; ++n)
        woff[n] = (unsigned int)(wn * 64 + n * 16 + l15) * (unsigned int)K + hi * 8;

    f32x4 acc[4][4] = {};
    const int S = K / 32;                        // 32-wide K-steps (8 or 16)

    bf16x8 fa0[4], fb0[4], fa1[4], fb1[4];
    auto LOAD = [&](int s, bf16x8 (&fA)[4], bf16x8 (&fB)[4]) {
        const unsigned short* Asrc = (s < 8) ? Xb : Yb;
        const unsigned int ak = (unsigned int)(s & 7) * 32u;
#pragma unroll
        for (int m = 0; m < 4; ++m)
            fA[m] = *(const bf16x8*)(Asrc + aoff[m] + ak);
#pragma unroll
        for (int n = 0; n < 4; ++n)
            fB[n] = *(const bf16x8*)(Wt + woff[n] + (unsigned int)s * 32u);
    };
    auto DOMFMA = [&](bf16x8 (&fA)[4], bf16x8 (&fB)[4]) {
#pragma unroll
        for (int m = 0; m < 4; ++m)
#pragma unroll
            for (int n = 0; n < 4; ++n)
                acc[m][n] = __builtin_amdgcn_mfma_f32_16x16x32_bf16(fA[m], fB[n], acc[m][n], 0, 0, 0);
    };

    LOAD(0, fa0, fb0);
    for (int s = 0; s < S; s += 2) {
        LOAD(s + 1, fa1, fb1);                   // in flight over MFMA(fa0)
        DOMFMA(fa0, fb0);
        if (s + 2 < S) LOAD(s + 2, fa0, fb0);    // in flight over MFMA(fa1)
        DOMFMA(fa1, fb1);
    }

    // epilogue through LDS: two 64-row halves; dense int4 stores
    for (int half = 0; half < 2; ++half) {
        __syncthreads();
        if (wm == half) {
#pragma unroll
            for (int m = 0; m < 4; ++m) {
#pragma unroll
                for (int j = 0; j < 4; ++j) {
                    int rl = m * 16 + hi * 4 + j;            // 0..63
                    int grow = row0 + half * 64 + rl;
                    if (grow < M) {
                        float di = dinv[grow];
#pragma unroll
                        for (int n = 0; n < 4; ++n) {
                            int colc = wn * 64 + n * 16 + l15;
                            float v = (acc[m][n][j] + cvec[colc]) * di;
                            *(unsigned short*)(ldsb + rl * 512 + colc * 2) = f2bf(v);
                        }
                    }
                }
            }
        }
        __syncthreads();
#pragma unroll
        for (int p = 0; p < 4; ++p) {
            int rl = p * 16 + (tid >> 5);
            int cb = tid & 31;
            int grow = row0 + half * 64 + rl;
            if (grow < M)
                *(int4*)(out + (size_t)grow * 256 + cb * 8) = *(const int4*)(ldsb + rl * 512 + cb * 16);
        }
    }
}

// ---------------- aggregation: Y[i] = dinv[i]*(U[i] + sum_{j in in(i)} U[j]) + d ----------------
// TWO nodes per wave, interleaved 8+8-deep gather streams (16 outstanding
// 512B row-gathers per wave) for memory-level parallelism.
__global__ __launch_bounds__(256)
void k_agg(const unsigned short* __restrict__ U, const int* __restrict__ rowptr,
           const int* __restrict__ col, const float* __restrict__ dinv,
           const float* __restrict__ dvec, unsigned short* __restrict__ Y, int N) {
    int wave = (blockIdx.x * 256 + threadIdx.x) >> 6;
    int lane = threadIdx.x & 63;
    int nA = wave * 2, nB = nA + 1;
    if (nA >= N) return;
    const bool hasB = (nB < N);
    const size_t loff = (size_t)lane * 4;

    ushort4 sa = *(const ushort4*)(U + (size_t)nA * 256 + loff);
    float a0 = bf2f(sa.x), a1 = bf2f(sa.y), a2 = bf2f(sa.z), a3 = bf2f(sa.w);
    float b0 = 0.f, b1 = 0.f, b2 = 0.f, b3 = 0.f;
    int eA = rowptr[nA], endA = rowptr[nA + 1];
    int eB = 0, endB = 0;
    if (hasB) {
        ushort4 sb = *(const ushort4*)(U + (size_t)nB * 256 + loff);
        b0 = bf2f(sb.x); b1 = bf2f(sb.y); b2 = bf2f(sb.z); b3 = bf2f(sb.w);
        eB = rowptr[nB]; endB = rowptr[nB + 1];
    }

    // joint phase: 8 gathers per node in flight (16 total)
    while (eA + 8 <= endA && eB + 8 <= endB) {
        int sA[8], sB[8];
#pragma unroll
        for (int u = 0; u < 8; ++u) {
            sA[u] = __builtin_amdgcn_readfirstlane(col[eA + u]);
            sB[u] = __builtin_amdgcn_readfirstlane(col[eB + u]);
        }
        ushort4 vA[8], vB[8];
#pragma unroll
        for (int u = 0; u < 8; ++u) {
            vA[u] = *(const ushort4*)(U + (size_t)sA[u] * 256 + loff);
            vB[u] = *(const ushort4*)(U + (size_t)sB[u] * 256 + loff);
        }
#pragma unroll
        for (int u = 0; u < 8; ++u) {
            a0 += bf2f(vA[u].x); a1 += bf2f(vA[u].y);
            a2 += bf2f(vA[u].z); a3 += bf2f(vA[u].w);
            b0 += bf2f(vB[u].x); b1 += bf2f(vB[u].y);
            b2 += bf2f(vB[u].z); b3 += bf2f(vB[u].w);
        }
        eA += 8; eB += 8;
    }
    // tails: 8-deep then scalar, per node
    for (; eA + 8 <= endA; eA += 8) {
        int s[8]; ushort4 v[8];
#pragma unroll
        for (int u = 0; u < 8; ++u) s[u] = __builtin_amdgcn_readfirstlane(col[eA + u]);
#pragma unroll
        for (int u = 0; u < 8; ++u) v[u] = *(const ushort4*)(U + (size_t)s[u] * 256 + loff);
#pragma unroll
        for (int u = 0; u < 8; ++u) {
            a0 += bf2f(v[u].x); a1 += bf2f(v[u].y);
            a2 += bf2f(v[u].z); a3 += bf2f(v[u].w);
        }
    }
    for (; eA < endA; ++eA) {
        int s = __builtin_amdgcn_readfirstlane(col[eA]);
        ushort4 v = *(const ushort4*)(U + (size_t)s * 256 + loff);
        a0 += bf2f(v.x); a1 += bf2f(v.y); a2 += bf2f(v.z); a3 += bf2f(v.w);
    }
    if (hasB) {
        for (; eB + 8 <= endB; eB += 8) {
            int s[8]; ushort4 v[8];
#pragma unroll
            for (int u = 0; u < 8; ++u) s[u] = __builtin_amdgcn_readfirstlane(col[eB + u]);
#pragma unroll
            for (int u = 0; u < 8; ++u) v[u] = *(const ushort4*)(U + (size_t)s[u] * 256 + loff);
#pragma unroll
            for (int u = 0; u < 8; ++u) {
                b0 += bf2f(v[u].x); b1 += bf2f(v[u].y);
                b2 += bf2f(v[u].z); b3 += bf2f(v[u].w);
            }
        }
        for (; eB < endB; ++eB) {
            int s = __builtin_amdgcn_readfirstlane(col[eB]);
            ushort4 v = *(const ushort4*)(U + (size_t)s * 256 + loff);
            b0 += bf2f(v.x); b1 += bf2f(v.y); b2 += bf2f(v.z); b3 += bf2f(v.w);
        }
    }

    const int f = lane * 4;
    const float d0 = dvec[f + 0], d1 = dvec[f + 1], d2 = dvec[f + 2], d3 = dvec[f + 3];
    {
        float di = dinv[nA];
        ushort4 o;
        o.x = f2bf(a0 * di + d0); o.y = f2bf(a1 * di + d1);
        o.z = f2bf(a2 * di + d2); o.w = f2bf(a3 * di + d3);
        *(ushort4*)(Y + (size_t)nA * 256 + loff) = o;
    }
    if (hasB) {
        float di = dinv[nB];
        ushort4 o;
        o.x = f2bf(b0 * di + d0); o.y = f2bf(b1 * di + d1);
        o.z = f2bf(b2 * di + d2); o.w = f2bf(b3 * di + d3);
        *(ushort4*)(Y + (size_t)nB * 256 + loff) = o;
    }
}

// ---------------- pooling (batch is sorted) ----------------
__global__ __launch_bounds__(256)
void k_pool(const unsigned short* __restrict__ Y, const int* __restrict__ batch, int N,
            float* __restrict__ psum, unsigned int* __restrict__ pkey, int* __restrict__ pcnt,
            const int* __restrict__ flags) {
    int f = threadIdx.x;
    int base = blockIdx.x * 64;
    if (base >= N) return;
    int i64 = flags[1];
    int g0 = ldi(batch, base, i64); int curg = g0 < 0 ? 0 : (g0 > 63 ? 63 : g0);
    float s = 0.f, mx = -__builtin_inff(); int cnt = 0;
#pragma unroll 4
    for (int r = 0; r < 64; ++r) {
        int node = base + r;
        if (node >= N) break;
        int g = ldi(batch, node, i64); g = g < 0 ? 0 : (g > 63 ? 63 : g);
        if (g != curg) {
            atomicAdd(&psum[curg * 256 + f], s);
            atomicMax(&pkey[curg * 256 + f], fenc(mx));
            if (f == 0) atomicAdd(&pcnt[curg], cnt);
            curg = g; s = 0.f; mx = -__builtin_inff(); cnt = 0;
        }
        float v = bf2f(Y[(size_t)node * 256 + f]);
        s += v; mx = fmaxf(mx, v); ++cnt;
    }
    atomicAdd(&psum[curg * 256 + f], s);
    atomicMax(&pkey[curg * 256 + f], fenc(mx));
    if (f == 0) atomicAdd(&pcnt[curg], cnt);
}

// ---------------- classifier ----------------
__global__ __launch_bounds__(64)
void k_cls(const float* __restrict__ psum, const unsigned int* __restrict__ pkey,
           const int* __restrict__ pcnt, const void* __restrict__ clsw,
           const void* __restrict__ clsb, float* __restrict__ outf,
           unsigned short* __restrict__ outu, const int* __restrict__ flags) {
    __shared__ float pooled[256];
    int g = blockIdx.x, c = threadIdx.x;
    int f = flags[0];
    int cnt = pcnt[g];
    for (int m = c; m < 256; m += 64) {
        float mean = psum[g * 256 + m] / (float)(cnt > 0 ? cnt : 1);
        float mx = (cnt > 0) ? fdec(pkey[g * 256 + m]) : 0.f;
        pooled[m] = mean + mx;
    }
    __syncthreads();
    float a = ldf(clsb, c, f);
#pragma unroll 8
    for (int m = 0; m < 256; ++m) a += pooled[m] * ldf(clsw, (size_t)m * 64 + c, f);
    if (f) outf[g * 64 + c] = a;
    else   outu[g * 64 + c] = f2bf(a);
}

extern "C" void kernel_launch(void* const* d_in, const int* in_sizes, int n_in,
                              void* d_out, int out_size, void* d_ws, size_t ws_size,
                              hipStream_t stream) {
    const void*           X     = d_in[0];
    const int*            EI    = (const int*)d_in[1];
    const int*            BATCH = (const int*)d_in[3];
    const void*           PREW  = d_in[4];
    const void*           PREB  = d_in[5];
    const void*           GCNW  = d_in[6];
    const void*           GCNB  = d_in[7];
    const void*           CLSW  = d_in[8];
    const void*           CLSB  = d_in[9];

    const int N = in_sizes[3];
    const int E = in_sizes[1] / 2;
    const int NB = (N + 255) / 256;

    char* ws = (char*)d_ws;
    size_t off = 0;
    auto alloc = [&](size_t b) { size_t o = off; off += (b + 255) & ~(size_t)255; return o; };
    int*            flags  = (int*)(ws + alloc(256));
    float*          dinv   = (float*)(ws + alloc((size_t)N * 4));
    int*            hist   = (int*)(ws + alloc((size_t)N * 4));
    int*            cursor = (int*)(ws + alloc((size_t)N * 4));
    int*            rowptr = (int*)(ws + alloc((size_t)(N + 1) * 4));
    int*            pre    = (int*)(ws + alloc((size_t)N * 4));
    int*            bsum   = (int*)(ws + alloc((size_t)NB * 4));
    int*            boff   = (int*)(ws + alloc((size_t)NB * 4));
    int*            col    = (int*)(ws + alloc((size_t)E * 4));
    unsigned short* Pb     = (unsigned short*)(ws + alloc(4 * 65536 * 2));
    unsigned short* Gt     = (unsigned short*)(ws + alloc(4 * 65536 * 2));
    unsigned short* Wt0    = (unsigned short*)(ws + alloc(256 * 256 * 2));
    unsigned short* Wt1    = (unsigned short*)(ws + alloc(256 * 512 * 2));
    float*          cvec   = (float*)(ws + alloc(512 * 4));
    float*          dvec   = (float*)(ws + alloc(512 * 4));
    float*          psum   = (float*)(ws + alloc(64 * 256 * 4));
    unsigned int*   pkey   = (unsigned int*)(ws + alloc(64 * 256 * 4));
    int*            pcnt   = (int*)(ws + alloc(64 * 4));
    unsigned short* Xb     = (unsigned short*)(ws + alloc((size_t)N * 256 * 2));
    unsigned short* U      = (unsigned short*)(ws + alloc((size_t)N * 256 * 2));
    unsigned short* Y      = (unsigned short*)(ws + alloc((size_t)N * 256 * 2));

    int xstride = (in_sizes[0] / 2) / 1024; if (xstride < 1) xstride = 1;
    int estride = E / 1024;                 if (estride < 1) estride = 1;
    int zt = 2 * N + 32768 + 64;
    k_init<<<1 + (zt + 255) / 256, 256, 0, stream>>>((const unsigned short*)X, xstride,
                                                     EI, estride, flags,
                                                     hist, cursor, psum, pkey, pcnt, N);

    size_t xelem = (size_t)N * 256;
    k_cvt<<<(int)((xelem / 8 + 255) / 256), 256, 0, stream>>>(X, Xb, xelem, flags);

    k_hist<<<(E + 255) / 256, 256, 0, stream>>>(EI, E, N, hist, flags);
    k_scan1<<<NB, 256, 0, stream>>>(hist, pre, bsum, N);
    k_scan2<<<1, 256, 0, stream>>>(bsum, boff, rowptr, NB, N);
    k_scan3<<<NB, 256, 0, stream>>>(hist, pre, boff, rowptr, dinv, N);
    k_scatter<<<(E + 255) / 256, 256, 0, stream>>>(EI, E, N, rowptr, cursor, col, flags);

    k_cvtw<<<dim3(16, 4), 256, 0, stream>>>(PREW, GCNW, Pb, Gt, flags);
    k_prepw<<<dim3(64, 3), 256, 0, stream>>>(Pb, Gt, Wt0, Wt1);
    k_prepb<<<2, 256, 0, stream>>>(PREB, Gt, GCNB, cvec, dvec, flags);

    int ggrid = (N + 127) / 128;
    int agrid = (N + 7) / 8;                      // 2 nodes/wave, 4 waves/block
    k_gemm<<<ggrid, 512, 0, stream>>>(Xb, U, Wt0, cvec, dinv, U, N, 256);
    k_agg<<<agrid, 256, 0, stream>>>(U, rowptr, col, dinv, dvec, Y, N);
    k_gemm<<<ggrid, 512, 0, stream>>>(Xb, Y, Wt1, cvec + 256, dinv, U, N, 512);
    k_agg<<<agrid, 256, 0, stream>>>(U, rowptr, col, dinv, dvec + 256, Y, N);
    k_pool<<<(N + 63) / 64, 256, 0, stream>>>(Y, BATCH, N, psum, pkey, pcnt, flags);
    k_cls<<<64, 64, 0, stream>>>(psum, pkey, pcnt, CLSW, CLSB,
                                 (float*)d_out, (unsigned short*)d_out, flags);
}

// Round 14
// 404.747 us; speedup vs baseline: 1.0225x; 1.0225x over previous
//
#include <hip/hip_runtime.h>

typedef __attribute__((ext_vector_type(8))) short bf16x8;
typedef __attribute__((ext_vector_type(4))) float f32x4;

__device__ inline float bf2f(unsigned short u) {
    union { float f; unsigned int i; } v; v.i = ((unsigned int)u) << 16; return v.f;
}
__device__ inline unsigned short f2bf(float f) {
    union { float f; unsigned int u; } v; v.f = f;
    unsigned int x = v.u;
    unsigned int r = x + 0x7FFFu + ((x >> 16) & 1u);
    return (unsigned short)(r >> 16);
}
// order-preserving float <-> uint for atomicMax
__device__ inline unsigned int fenc(float x) {
    union { float f; unsigned int u; } v; v.f = x;
    return (v.u & 0x80000000u) ? ~v.u : (v.u | 0x80000000u);
}
__device__ inline float fdec(unsigned int k) {
    union { float f; unsigned int u; } v;
    v.u = (k & 0x80000000u) ? (k & 0x7FFFFFFFu) : ~k;
    return v.f;
}
// dual-format loads: f32flag ? float32 buffer : bf16 buffer
__device__ inline float ldf(const void* p, size_t i, int f32) {
    return f32 ? ((const float*)p)[i] : bf2f(((const unsigned short*)p)[i]);
}
// i64flag ? int64 buffer (values < 2^31, take low word) : int32 buffer
__device__ inline int ldi(const int* p, size_t i, int i64) {
    return i64 ? p[2 * i] : p[i];
}
__device__ inline int4 cvt8(float4 a, float4 b) {
    int4 o;
    o.x = (int)f2bf(a.x) | ((int)f2bf(a.y) << 16);
    o.y = (int)f2bf(a.z) | ((int)f2bf(a.w) << 16);
    o.z = (int)f2bf(b.x) | ((int)f2bf(b.y) << 16);
    o.w = (int)f2bf(b.z) | ((int)f2bf(b.w) << 16);
    return o;
}

// ---------------- zero scratch + format detection (fused; block 0 = detect) ----------------
__global__ void k_init(const unsigned short* __restrict__ xu, int xstride,
                       const int* __restrict__ ei, int estride, int* __restrict__ flags,
                       int* __restrict__ hist, int* __restrict__ cursor,
                       float* __restrict__ psum, unsigned int* __restrict__ pkey,
                       int* __restrict__ pcnt, int N) {
    if (blockIdx.x == 0) {
        __shared__ int cnt, orv;
        if (threadIdx.x == 0) { cnt = 0; orv = 0; }
        __syncthreads();
        int c = 0, o = 0;
        for (int s = 0; s < 4; ++s) {
            int j = threadIdx.x * 4 + s;               // 0..1023
            size_t k = (size_t)j * xstride;            // < xelems/2
            unsigned short u = xu[2 * k];              // even ushort
            int e = (u >> 7) & 0xFF;
            if (e >= 100 && e <= 140) ++c;             // sane bf16 exponent?
            size_t idx = (size_t)j * estride;          // < E
            o |= ei[2 * idx + 1];                      // odd word
        }
        atomicAdd(&cnt, c); atomicOr(&orv, o);
        __syncthreads();
        if (threadIdx.x == 0) {
            flags[0] = (cnt < 768) ? 1 : 0;   // 1 => floats are f32
            flags[1] = (orv == 0) ? 1 : 0;    // 1 => ints are int64
        }
        return;
    }
    int t = (blockIdx.x - 1) * 256 + threadIdx.x;
    if (t < N) hist[t] = 0;
    else if (t < 2 * N) cursor[t - N] = 0;
    else if (t < 2 * N + 16384) psum[t - 2 * N] = 0.f;
    else if (t < 2 * N + 32768) pkey[t - 2 * N - 16384] = 0u;
    else if (t < 2 * N + 32768 + 64) pcnt[t - 2 * N - 32768] = 0;
}

// ---------------- weight convert + transpose ----------------
__global__ __launch_bounds__(256)
void k_cvtw(const void* __restrict__ pre_w, const void* __restrict__ gcn_w,
            unsigned short* __restrict__ Pb, unsigned short* __restrict__ Gt,
            const int* __restrict__ flags) {
    __shared__ float tile[64][65];
    const int i = blockIdx.y;
    const int m0 = (blockIdx.x & 3) * 64;
    const int n0 = (blockIdx.x >> 2) * 64;
    const int f = flags[0];
    const size_t base = (size_t)i * 65536;
#pragma unroll
    for (int q = 0; q < 16; ++q) {
        int idx = q * 256 + threadIdx.x;
        int r = idx >> 6, c = idx & 63;
        size_t src = base + (size_t)(m0 + r) * 256 + n0 + c;
        Pb[src] = f2bf(ldf(pre_w, src, f));
        tile[r][c] = ldf(gcn_w, src, f);
    }
    __syncthreads();
#pragma unroll
    for (int q = 0; q < 16; ++q) {
        int idx = q * 256 + threadIdx.x;
        int r = idx >> 6, c = idx & 63;
        Gt[base + (size_t)(n0 + r) * 256 + m0 + c] = f2bf(tile[c][r]);
    }
}

// ---------------- weight folding via MFMA ----------------
__global__ __launch_bounds__(256)
void k_prepw(const unsigned short* __restrict__ Pb, const unsigned short* __restrict__ Gt,
             unsigned short* __restrict__ Wt0, unsigned short* __restrict__ Wt1) {
    const int which = blockIdx.y;
    const int wid = threadIdx.x >> 6, lane = threadIdx.x & 63;
    const int tile = blockIdx.x * 4 + wid;       // 0..255
    const int n0 = (tile >> 4) * 16, k0 = (tile & 15) * 16;
    const int l15 = lane & 15, hi = lane >> 4;
    size_t base0, base1 = 0;
    if (which == 0)      { base0 = 0; base1 = 65536; }
    else if (which == 1) { base0 = 2 * 65536; }
    else                 { base0 = 3 * 65536; }
    f32x4 acc0 = {}, acc1 = {};
    const unsigned short* ga = Gt + base0 + (size_t)(n0 + l15) * 256 + hi * 8;
    const unsigned short* pa = Pb + base0 + (size_t)(k0 + l15) * 256 + hi * 8;
    const unsigned short* gb = Gt + base1 + (size_t)(n0 + l15) * 256 + hi * 8;
    const unsigned short* pb = Pb + base1 + (size_t)(k0 + l15) * 256 + hi * 8;
#pragma unroll
    for (int kt = 0; kt < 8; ++kt) {
        bf16x8 a0 = *(const bf16x8*)(ga + kt * 32);
        bf16x8 b0 = *(const bf16x8*)(pa + kt * 32);
        acc0 = __builtin_amdgcn_mfma_f32_16x16x32_bf16(a0, b0, acc0, 0, 0, 0);
        if (which == 0) {
            bf16x8 a1 = *(const bf16x8*)(gb + kt * 32);
            bf16x8 b1 = *(const bf16x8*)(pb + kt * 32);
            acc1 = __builtin_amdgcn_mfma_f32_16x16x32_bf16(a1, b1, acc1, 0, 0, 0);
        }
    }
#pragma unroll
    for (int j = 0; j < 4; ++j) {
        int n = n0 + hi * 4 + j;
        int k = k0 + l15;
        if (which == 0)      Wt0[(size_t)n * 256 + k]       = f2bf(2.f * acc0[j] + acc1[j]);
        else if (which == 1) Wt1[(size_t)n * 512 + k]       = f2bf(2.f * acc0[j]);
        else                 Wt1[(size_t)n * 512 + 256 + k] = f2bf(acc0[j]);
    }
}

// ---------------- bias folding (uses Gt: contiguous bf16 rows) ----------------
__global__ __launch_bounds__(256)
void k_prepb(const void* __restrict__ pre_b, const unsigned short* __restrict__ Gt,
             const void* __restrict__ gcn_b,
             float* __restrict__ cvec, float* __restrict__ dvec,
             const int* __restrict__ flags) {
    __shared__ float pb[2][256];
    const int l = blockIdx.x, n = threadIdx.x;
    const int f = flags[0];
    pb[0][n] = ldf(pre_b, (size_t)(l * 2 + 0) * 256 + n, f);
    pb[1][n] = ldf(pre_b, (size_t)(l * 2 + 1) * 256 + n, f);
    __syncthreads();
    const unsigned short* g0 = Gt + (size_t)(l * 2 + 0) * 65536 + (size_t)n * 256;
    const unsigned short* g1 = Gt + (size_t)(l * 2 + 1) * 65536 + (size_t)n * 256;
    float a = 0.f, b = 0.f;
#pragma unroll 4
    for (int mc = 0; mc < 32; ++mc) {
        bf16x8 v0 = *(const bf16x8*)(g0 + mc * 8);
        bf16x8 v1 = *(const bf16x8*)(g1 + mc * 8);
#pragma unroll
        for (int u = 0; u < 8; ++u) {
            a += pb[0][mc * 8 + u] * bf2f((unsigned short)v0[u]);
            b += pb[1][mc * 8 + u] * bf2f((unsigned short)v1[u]);
        }
    }
    cvec[l * 256 + n] = 2.f * a + b;
    dvec[l * 256 + n] = 2.f * ldf(gcn_b, (size_t)(l * 2 + 0) * 256 + n, f)
                            + ldf(gcn_b, (size_t)(l * 2 + 1) * 256 + n, f);
}

// ---------------- CSR build ----------------
__global__ void k_hist(const int* __restrict__ ei, int E, int N,
                       int* __restrict__ hist, const int* __restrict__ flags) {
    int e = blockIdx.x * 256 + threadIdx.x;
    if (e >= E) return;
    int i64 = flags[1];
    int d = ldi(ei, (size_t)E + e, i64); d = d < 0 ? 0 : (d >= N ? N - 1 : d);
    atomicAdd(&hist[d], 1);
}

__global__ __launch_bounds__(256)
void k_scan1(const int* __restrict__ hist, int* __restrict__ pre,
             int* __restrict__ bsum, int N) {
    __shared__ int s[256];
    int i = blockIdx.x * 256 + threadIdx.x;
    int v = (i < N) ? hist[i] : 0;
    s[threadIdx.x] = v;
    __syncthreads();
    for (int off = 1; off < 256; off <<= 1) {
        int t = (threadIdx.x >= off) ? s[threadIdx.x - off] : 0;
        __syncthreads();
        s[threadIdx.x] += t;
        __syncthreads();
    }
    if (i < N) pre[i] = s[threadIdx.x] - v;          // exclusive within block
    if (threadIdx.x == 255) bsum[blockIdx.x] = s[255];
}

__global__ __launch_bounds__(256)
void k_scan2(const int* __restrict__ bsum, int* __restrict__ boff,
             int* __restrict__ rowptr, int nb, int N) {
    __shared__ int s[256];
    int t = threadIdx.x;
    int v = (t < nb) ? bsum[t] : 0;
    s[t] = v;
    __syncthreads();
    for (int off = 1; off < 256; off <<= 1) {
        int x = (t >= off) ? s[t - off] : 0;
        __syncthreads();
        s[t] += x;
        __syncthreads();
    }
    if (t < nb) boff[t] = s[t] - v;                  // exclusive block offset
    if (t == nb - 1) rowptr[N] = s[t];               // grand total
}

__global__ __launch_bounds__(256)
void k_scan3(const int* __restrict__ hist, const int* __restrict__ pre,
             const int* __restrict__ boff, int* __restrict__ rowptr,
             float* __restrict__ dinv, int N) {
    int i = blockIdx.x * 256 + threadIdx.x;
    if (i < N) {
        rowptr[i] = pre[i] + boff[blockIdx.x];
        dinv[i] = rsqrtf((float)(hist[i] + 1));
    }
}

__global__ void k_scatter(const int* __restrict__ ei, int E, int N,
                          const int* __restrict__ rowptr, int* __restrict__ cursor,
                          int* __restrict__ col, const int* __restrict__ flags) {
    int e = blockIdx.x * 256 + threadIdx.x;
    if (e >= E) return;
    int i64 = flags[1];
    int s = ldi(ei, (size_t)e, i64);     s = s < 0 ? 0 : (s >= N ? N - 1 : s);
    int d = ldi(ei, (size_t)E + e, i64); d = d < 0 ? 0 : (d >= N ? N - 1 : d);
    int pos = rowptr[d] + atomicAdd(&cursor[d], 1);
    col[pos] = s;
}

// ---------------- GEMM1 (fused X->bf16 convert): U = dinv*(X@W0 + c), also emits Xb ----------------
// K=256. A read from raw X (f32 or bf16 per flag); converted chunks written to
// LDS (swizzled) AND to Xb (each element staged exactly once across the grid).
// 128x256 tile, 512 thr = 8 waves (2x4), register prefetch of step k+1.
__global__ __launch_bounds__(512)
void k_gemm1(const void* __restrict__ Xraw, unsigned short* __restrict__ Xb,
             const unsigned short* __restrict__ Wt, const float* __restrict__ cvec,
             const float* __restrict__ dinv, unsigned short* __restrict__ out,
             int M, const int* __restrict__ flags) {
    __shared__ char ldsb[49152];                 // A tile 16KB @0, W tile 32KB @16384
    const int tid = threadIdx.x;
    const int lane = tid & 63;
    const int wid = tid >> 6;                    // 0..7
    const int wm = wid >> 2, wn = wid & 3;       // 2 x 4 waves
    const int l15 = lane & 15, hi = lane >> 4;
    const int row0 = blockIdx.x * 128;
    const int xf32 = flags[0];
    const int K = 256;

    // A-chunk coords: chunk0 = tid (rows 0..63), chunk1 = 512+tid (rows 64..127)
    const int r0 = tid >> 3, cb0 = tid & 7;
    const int r1 = (512 + tid) >> 3, cb1 = tid & 7;
    int g0 = row0 + r0; if (g0 > M - 1) g0 = M - 1;
    int g1 = row0 + r1; if (g1 > M - 1) g1 = M - 1;
    const size_t ab0 = (size_t)g0 * 256 + cb0 * 8;
    const size_t ab1 = (size_t)g1 * 256 + cb1 * 8;

    f32x4 acc[4][4] = {};
    int4 ra0, ra1, rw[4];
    float4 rf0a, rf0b, rf1a, rf1b;

    auto LOADA = [&](int ak) {
        if (xf32) {
            const float* s0 = (const float*)Xraw + ab0 + ak;
            rf0a = *(const float4*)s0; rf0b = *(const float4*)(s0 + 4);
            const float* s1 = (const float*)Xraw + ab1 + ak;
            rf1a = *(const float4*)s1; rf1b = *(const float4*)(s1 + 4);
        } else {
            ra0 = *(const int4*)((const unsigned short*)Xraw + ab0 + ak);
            ra1 = *(const int4*)((const unsigned short*)Xraw + ab1 + ak);
        }
    };
    auto LOADW = [&](int k0) {
#pragma unroll
        for (int q = 0; q < 4; ++q) {
            int id = q * 512 + tid; int r = id >> 3, cb = id & 7;
            rw[q] = *(const int4*)(Wt + (size_t)r * K + k0 + cb * 8);
        }
    };

    LOADA(0); LOADW(0);
    for (int kt = 0; kt < 4; ++kt) {
        const int k0 = kt * 64;
        __syncthreads();   // prior MFMA's LDS reads done
        {
            int4 v0 = xf32 ? cvt8(rf0a, rf0b) : ra0;
            int4 v1 = xf32 ? cvt8(rf1a, rf1b) : ra1;
            int sw0 = (cb0 * 16) ^ ((r0 & 7) << 4);
            int sw1 = (cb1 * 16) ^ ((r1 & 7) << 4);
            *(int4*)(ldsb + r0 * 128 + sw0) = v0;
            *(int4*)(ldsb + r1 * 128 + sw1) = v1;
            *(int4*)(Xb + ab0 + k0) = v0;            // emit bf16 X for gemm2
            *(int4*)(Xb + ab1 + k0) = v1;
        }
#pragma unroll
        for (int q = 0; q < 4; ++q) {
            int id = q * 512 + tid; int r = id >> 3, cb = id & 7;
            int sw = (cb * 16) ^ ((r & 7) << 4);
            *(int4*)(ldsb + 16384 + r * 128 + sw) = rw[q];
        }
        __syncthreads();
        if (kt + 1 < 4) { LOADA((kt + 1) * 64); LOADW((kt + 1) * 64); }
#pragma unroll
        for (int kk = 0; kk < 2; ++kk) {
            bf16x8 af[4], bfr[4];
            int byte = kk * 64 + (hi << 4);
#pragma unroll
            for (int m = 0; m < 4; ++m) {
                int r = wm * 64 + m * 16 + l15;
                af[m] = *(const bf16x8*)(ldsb + r * 128 + (byte ^ ((r & 7) << 4)));
            }
#pragma unroll
            for (int n = 0; n < 4; ++n) {
                int r = wn * 64 + n * 16 + l15;
                bfr[n] = *(const bf16x8*)(ldsb + 16384 + r * 128 + (byte ^ ((r & 7) << 4)));
            }
#pragma unroll
            for (int m = 0; m < 4; ++m)
#pragma unroll
                for (int n = 0; n < 4; ++n)
                    acc[m][n] = __builtin_amdgcn_mfma_f32_16x16x32_bf16(af[m], bfr[n], acc[m][n], 0, 0, 0);
        }
    }
    // epilogue through LDS: two 64-row halves; dense int4 stores
    for (int half = 0; half < 2; ++half) {
        __syncthreads();
        if (wm == half) {
#pragma unroll
            for (int m = 0; m < 4; ++m) {
#pragma unroll
                for (int j = 0; j < 4; ++j) {
                    int rl = m * 16 + hi * 4 + j;            // 0..63
                    int grow = row0 + half * 64 + rl;
                    if (grow < M) {
                        float di = dinv[grow];
#pragma unroll
                        for (int n = 0; n < 4; ++n) {
                            int colc = wn * 64 + n * 16 + l15;
                            float v = (acc[m][n][j] + cvec[colc]) * di;
                            *(unsigned short*)(ldsb + rl * 512 + colc * 2) = f2bf(v);
                        }
                    }
                }
            }
        }
        __syncthreads();
#pragma unroll
        for (int p = 0; p < 4; ++p) {
            int rl = p * 16 + (tid >> 5);
            int cb = tid & 31;
            int grow = row0 + half * 64 + rl;
            if (grow < M)
                *(int4*)(out + (size_t)grow * 256 + cb * 8) = *(const int4*)(ldsb + rl * 512 + cb * 16);
        }
    }
}

// ---------------- GEMM2: out[i,:] = dinv[i] * ([Xb|Yb] @ W + c) ----------------
// R12 best-measured: 128x256 tile, BK=64, 512 thr = 8 waves (2x4),
// XOR-swizzled LDS, register prefetch of K-step k+1 before MFMA(k).
__global__ __launch_bounds__(512)
void k_gemm(const unsigned short* __restrict__ Xb, const unsigned short* __restrict__ Yb,
            const unsigned short* __restrict__ Wt, const float* __restrict__ cvec,
            const float* __restrict__ dinv, unsigned short* __restrict__ out,
            int M, int K) {
    __shared__ char ldsb[49152];                 // A tile 16KB @0, W tile 32KB @16384
    const int tid = threadIdx.x;
    const int lane = tid & 63;
    const int wid = tid >> 6;                    // 0..7
    const int wm = wid >> 2, wn = wid & 3;       // 2 x 4 waves
    const int l15 = lane & 15, hi = lane >> 4;
    const int row0 = blockIdx.x * 128;

    const int ar = tid >> 3, acb = tid & 7;      // A-load coords (fixed per thread)
    int agrow = row0 + ar; if (agrow > M - 1) agrow = M - 1;
    const size_t abase = (size_t)agrow * 256 + acb * 8;

    f32x4 acc[4][4] = {};
    const int KT = K / 64;
    int4 ra[2], rw[4];

    // prologue: load K-step 0
    {
        const unsigned short* Asrc = Xb;
        ra[0] = *(const int4*)(Asrc + abase);
        {
            int id = 512 + tid; int r = id >> 3, cb = id & 7;
            int grow = row0 + r; if (grow > M - 1) grow = M - 1;
            ra[1] = *(const int4*)(Asrc + (size_t)grow * 256 + cb * 8);
        }
#pragma unroll
        for (int q = 0; q < 4; ++q) {
            int id = q * 512 + tid; int r = id >> 3, cb = id & 7;
            rw[q] = *(const int4*)(Wt + (size_t)r * K + cb * 8);
        }
    }

    for (int kt = 0; kt < KT; ++kt) {
        __syncthreads();   // prior MFMA's LDS reads done (no-op on first iter)
        // write staged registers to LDS (compiler inserts vmcnt wait here)
        {
            int sw = (acb * 16) ^ ((ar & 7) << 4);
            *(int4*)(ldsb + ar * 128 + sw) = ra[0];
            int id = 512 + tid; int r = id >> 3, cb = id & 7;
            int sw1 = (cb * 16) ^ ((r & 7) << 4);
            *(int4*)(ldsb + r * 128 + sw1) = ra[1];
        }
#pragma unroll
        for (int q = 0; q < 4; ++q) {
            int id = q * 512 + tid; int r = id >> 3, cb = id & 7;
            int sw = (cb * 16) ^ ((r & 7) << 4);
            *(int4*)(ldsb + 16384 + r * 128 + sw) = rw[q];
        }
        __syncthreads();
        // issue next K-step's loads EARLY (overlap with MFMA below)
        if (kt + 1 < KT) {
            const int k1 = (kt + 1) * 64;
            const unsigned short* Asrc = (k1 < 256) ? Xb : Yb;
            const int ak1 = (k1 < 256) ? k1 : k1 - 256;
            ra[0] = *(const int4*)(Asrc + abase + ak1);
            {
                int id = 512 + tid; int r = id >> 3, cb = id & 7;
                int grow = row0 + r; if (grow > M - 1) grow = M - 1;
                ra[1] = *(const int4*)(Asrc + (size_t)grow * 256 + ak1 + cb * 8);
            }
#pragma unroll
            for (int q = 0; q < 4; ++q) {
                int id = q * 512 + tid; int r = id >> 3, cb = id & 7;
                rw[q] = *(const int4*)(Wt + (size_t)r * K + k1 + cb * 8);
            }
        }
        // MFMA on current LDS tile
#pragma unroll
        for (int kk = 0; kk < 2; ++kk) {
            bf16x8 af[4], bfr[4];
            int byte = kk * 64 + (hi << 4);
#pragma unroll
            for (int m = 0; m < 4; ++m) {
                int r = wm * 64 + m * 16 + l15;
                af[m] = *(const bf16x8*)(ldsb + r * 128 + (byte ^ ((r & 7) << 4)));
            }
#pragma unroll
            for (int n = 0; n < 4; ++n) {
                int r = wn * 64 + n * 16 + l15;
                bfr[n] = *(const bf16x8*)(ldsb + 16384 + r * 128 + (byte ^ ((r & 7) << 4)));
            }
#pragma unroll
            for (int m = 0; m < 4; ++m)
#pragma unroll
                for (int n = 0; n < 4; ++n)
                    acc[m][n] = __builtin_amdgcn_mfma_f32_16x16x32_bf16(af[m], bfr[n], acc[m][n], 0, 0, 0);
        }
    }
    // epilogue through LDS: two 64-row halves; dense int4 stores
    for (int half = 0; half < 2; ++half) {
        __syncthreads();
        if (wm == half) {
#pragma unroll
            for (int m = 0; m < 4; ++m) {
#pragma unroll
                for (int j = 0; j < 4; ++j) {
                    int rl = m * 16 + hi * 4 + j;            // 0..63
                    int grow = row0 + half * 64 + rl;
                    if (grow < M) {
                        float di = dinv[grow];
#pragma unroll
                        for (int n = 0; n < 4; ++n) {
                            int colc = wn * 64 + n * 16 + l15;
                            float v = (acc[m][n][j] + cvec[colc]) * di;
                            *(unsigned short*)(ldsb + rl * 512 + colc * 2) = f2bf(v);
                        }
                    }
                }
            }
        }
        __syncthreads();
#pragma unroll
        for (int p = 0; p < 4; ++p) {
            int rl = p * 16 + (tid >> 5);
            int cb = tid & 31;
            int grow = row0 + half * 64 + rl;
            if (grow < M)
                *(int4*)(out + (size_t)grow * 256 + cb * 8) = *(const int4*)(ldsb + rl * 512 + cb * 16);
        }
    }
}

// ---------------- aggregation: Y[i] = dinv[i]*(U[i] + sum_{j in in(i)} U[j]) + d ----------------
// TWO nodes per wave, interleaved 8+8-deep gather streams (16 outstanding
// 512B row-gathers per wave) for memory-level parallelism.
__global__ __launch_bounds__(256)
void k_agg(const unsigned short* __restrict__ U, const int* __restrict__ rowptr,
           const int* __restrict__ col, const float* __restrict__ dinv,
           const float* __restrict__ dvec, unsigned short* __restrict__ Y, int N) {
    int wave = (blockIdx.x * 256 + threadIdx.x) >> 6;
    int lane = threadIdx.x & 63;
    int nA = wave * 2, nB = nA + 1;
    if (nA >= N) return;
    const bool hasB = (nB < N);
    const size_t loff = (size_t)lane * 4;

    ushort4 sa = *(const ushort4*)(U + (size_t)nA * 256 + loff);
    float a0 = bf2f(sa.x), a1 = bf2f(sa.y), a2 = bf2f(sa.z), a3 = bf2f(sa.w);
    float b0 = 0.f, b1 = 0.f, b2 = 0.f, b3 = 0.f;
    int eA = rowptr[nA], endA = rowptr[nA + 1];
    int eB = 0, endB = 0;
    if (hasB) {
        ushort4 sb = *(const ushort4*)(U + (size_t)nB * 256 + loff);
        b0 = bf2f(sb.x); b1 = bf2f(sb.y); b2 = bf2f(sb.z); b3 = bf2f(sb.w);
        eB = rowptr[nB]; endB = rowptr[nB + 1];
    }

    // joint phase: 8 gathers per node in flight (16 total)
    while (eA + 8 <= endA && eB + 8 <= endB) {
        int sA[8], sB[8];
#pragma unroll
        for (int u = 0; u < 8; ++u) {
            sA[u] = __builtin_amdgcn_readfirstlane(col[eA + u]);
            sB[u] = __builtin_amdgcn_readfirstlane(col[eB + u]);
        }
        ushort4 vA[8], vB[8];
#pragma unroll
        for (int u = 0; u < 8; ++u) {
            vA[u] = *(const ushort4*)(U + (size_t)sA[u] * 256 + loff);
            vB[u] = *(const ushort4*)(U + (size_t)sB[u] * 256 + loff);
        }
#pragma unroll
        for (int u = 0; u < 8; ++u) {
            a0 += bf2f(vA[u].x); a1 += bf2f(vA[u].y);
            a2 += bf2f(vA[u].z); a3 += bf2f(vA[u].w);
            b0 += bf2f(vB[u].x); b1 += bf2f(vB[u].y);
            b2 += bf2f(vB[u].z); b3 += bf2f(vB[u].w);
        }
        eA += 8; eB += 8;
    }
    // tails: 8-deep then scalar, per node
    for (; eA + 8 <= endA; eA += 8) {
        int s[8]; ushort4 v[8];
#pragma unroll
        for (int u = 0; u < 8; ++u) s[u] = __builtin_amdgcn_readfirstlane(col[eA + u]);
#pragma unroll
        for (int u = 0; u < 8; ++u) v[u] = *(const ushort4*)(U + (size_t)s[u] * 256 + loff);
#pragma unroll
        for (int u = 0; u < 8; ++u) {
            a0 += bf2f(v[u].x); a1 += bf2f(v[u].y);
            a2 += bf2f(v[u].z); a3 += bf2f(v[u].w);
        }
    }
    for (; eA < endA; ++eA) {
        int s = __builtin_amdgcn_readfirstlane(col[eA]);
        ushort4 v = *(const ushort4*)(U + (size_t)s * 256 + loff);
        a0 += bf2f(v.x); a1 += bf2f(v.y); a2 += bf2f(v.z); a3 += bf2f(v.w);
    }
    if (hasB) {
        for (; eB + 8 <= endB; eB += 8) {
            int s[8]; ushort4 v[8];
#pragma unroll
            for (int u = 0; u < 8; ++u) s[u] = __builtin_amdgcn_readfirstlane(col[eB + u]);
#pragma unroll
            for (int u = 0; u < 8; ++u) v[u] = *(const ushort4*)(U + (size_t)s[u] * 256 + loff);
#pragma unroll
            for (int u = 0; u < 8; ++u) {
                b0 += bf2f(v[u].x); b1 += bf2f(v[u].y);
                b2 += bf2f(v[u].z); b3 += bf2f(v[u].w);
            }
        }
        for (; eB < endB; ++eB) {
            int s = __builtin_amdgcn_readfirstlane(col[eB]);
            ushort4 v = *(const ushort4*)(U + (size_t)s * 256 + loff);
            b0 += bf2f(v.x); b1 += bf2f(v.y); b2 += bf2f(v.z); b3 += bf2f(v.w);
        }
    }

    const int f = lane * 4;
    const float d0 = dvec[f + 0], d1 = dvec[f + 1], d2 = dvec[f + 2], d3 = dvec[f + 3];
    {
        float di = dinv[nA];
        ushort4 o;
        o.x = f2bf(a0 * di + d0); o.y = f2bf(a1 * di + d1);
        o.z = f2bf(a2 * di + d2); o.w = f2bf(a3 * di + d3);
        *(ushort4*)(Y + (size_t)nA * 256 + loff) = o;
    }
    if (hasB) {
        float di = dinv[nB];
        ushort4 o;
        o.x = f2bf(b0 * di + d0); o.y = f2bf(b1 * di + d1);
        o.z = f2bf(b2 * di + d2); o.w = f2bf(b3 * di + d3);
        *(ushort4*)(Y + (size_t)nB * 256 + loff) = o;
    }
}

// ---------------- pooling (batch is sorted) ----------------
__global__ __launch_bounds__(256)
void k_pool(const unsigned short* __restrict__ Y, const int* __restrict__ batch, int N,
            float* __restrict__ psum, unsigned int* __restrict__ pkey, int* __restrict__ pcnt,
            const int* __restrict__ flags) {
    int f = threadIdx.x;
    int base = blockIdx.x * 64;
    if (base >= N) return;
    int i64 = flags[1];
    int g0 = ldi(batch, base, i64); int curg = g0 < 0 ? 0 : (g0 > 63 ? 63 : g0);
    float s = 0.f, mx = -__builtin_inff(); int cnt = 0;
#pragma unroll 4
    for (int r = 0; r < 64; ++r) {
        int node = base + r;
        if (node >= N) break;
        int g = ldi(batch, node, i64); g = g < 0 ? 0 : (g > 63 ? 63 : g);
        if (g != curg) {
            atomicAdd(&psum[curg * 256 + f], s);
            atomicMax(&pkey[curg * 256 + f], fenc(mx));
            if (f == 0) atomicAdd(&pcnt[curg], cnt);
            curg = g; s = 0.f; mx = -__builtin_inff(); cnt = 0;
        }
        float v = bf2f(Y[(size_t)node * 256 + f]);
        s += v; mx = fmaxf(mx, v); ++cnt;
    }
    atomicAdd(&psum[curg * 256 + f], s);
    atomicMax(&pkey[curg * 256 + f], fenc(mx));
    if (f == 0) atomicAdd(&pcnt[curg], cnt);
}

// ---------------- classifier ----------------
__global__ __launch_bounds__(64)
void k_cls(const float* __restrict__ psum, const unsigned int* __restrict__ pkey,
           const int* __restrict__ pcnt, const void* __restrict__ clsw,
           const void* __restrict__ clsb, float* __restrict__ outf,
           unsigned short* __restrict__ outu, const int* __restrict__ flags) {
    __shared__ float pooled[256];
    int g = blockIdx.x, c = threadIdx.x;
    int f = flags[0];
    int cnt = pcnt[g];
    for (int m = c; m < 256; m += 64) {
        float mean = psum[g * 256 + m] / (float)(cnt > 0 ? cnt : 1);
        float mx = (cnt > 0) ? fdec(pkey[g * 256 + m]) : 0.f;
        pooled[m] = mean + mx;
    }
    __syncthreads();
    float a = ldf(clsb, c, f);
#pragma unroll 8
    for (int m = 0; m < 256; ++m) a += pooled[m] * ldf(clsw, (size_t)m * 64 + c, f);
    if (f) outf[g * 64 + c] = a;
    else   outu[g * 64 + c] = f2bf(a);
}

extern "C" void kernel_launch(void* const* d_in, const int* in_sizes, int n_in,
                              void* d_out, int out_size, void* d_ws, size_t ws_size,
                              hipStream_t stream) {
    const void*           X     = d_in[0];
    const int*            EI    = (const int*)d_in[1];
    const int*            BATCH = (const int*)d_in[3];
    const void*           PREW  = d_in[4];
    const void*           PREB  = d_in[5];
    const void*           GCNW  = d_in[6];
    const void*           GCNB  = d_in[7];
    const void*           CLSW  = d_in[8];
    const void*           CLSB  = d_in[9];

    const int N = in_sizes[3];
    const int E = in_sizes[1] / 2;
    const int NB = (N + 255) / 256;

    char* ws = (char*)d_ws;
    size_t off = 0;
    auto alloc = [&](size_t b) { size_t o = off; off += (b + 255) & ~(size_t)255; return o; };
    int*            flags  = (int*)(ws + alloc(256));
    float*          dinv   = (float*)(ws + alloc((size_t)N * 4));
    int*            hist   = (int*)(ws + alloc((size_t)N * 4));
    int*            cursor = (int*)(ws + alloc((size_t)N * 4));
    int*            rowptr = (int*)(ws + alloc((size_t)(N + 1) * 4));
    int*            pre    = (int*)(ws + alloc((size_t)N * 4));
    int*            bsum   = (int*)(ws + alloc((size_t)NB * 4));
    int*            boff   = (int*)(ws + alloc((size_t)NB * 4));
    int*            col    = (int*)(ws + alloc((size_t)E * 4));
    unsigned short* Pb     = (unsigned short*)(ws + alloc(4 * 65536 * 2));
    unsigned short* Gt     = (unsigned short*)(ws + alloc(4 * 65536 * 2));
    unsigned short* Wt0    = (unsigned short*)(ws + alloc(256 * 256 * 2));
    unsigned short* Wt1    = (unsigned short*)(ws + alloc(256 * 512 * 2));
    float*          cvec   = (float*)(ws + alloc(512 * 4));
    float*          dvec   = (float*)(ws + alloc(512 * 4));
    float*          psum   = (float*)(ws + alloc(64 * 256 * 4));
    unsigned int*   pkey   = (unsigned int*)(ws + alloc(64 * 256 * 4));
    int*            pcnt   = (int*)(ws + alloc(64 * 4));
    unsigned short* Xb     = (unsigned short*)(ws + alloc((size_t)(N + 128) * 256 * 2));
    unsigned short* U      = (unsigned short*)(ws + alloc((size_t)N * 256 * 2));
    unsigned short* Y      = (unsigned short*)(ws + alloc((size_t)N * 256 * 2));

    int xstride = (in_sizes[0] / 2) / 1024; if (xstride < 1) xstride = 1;
    int estride = E / 1024;                 if (estride < 1) estride = 1;
    int zt = 2 * N + 32768 + 64;
    k_init<<<1 + (zt + 255) / 256, 256, 0, stream>>>((const unsigned short*)X, xstride,
                                                     EI, estride, flags,
                                                     hist, cursor, psum, pkey, pcnt, N);

    k_hist<<<(E + 255) / 256, 256, 0, stream>>>(EI, E, N, hist, flags);
    k_scan1<<<NB, 256, 0, stream>>>(hist, pre, bsum, N);
    k_scan2<<<1, 256, 0, stream>>>(bsum, boff, rowptr, NB, N);
    k_scan3<<<NB, 256, 0, stream>>>(hist, pre, boff, rowptr, dinv, N);
    k_scatter<<<(E + 255) / 256, 256, 0, stream>>>(EI, E, N, rowptr, cursor, col, flags);

    k_cvtw<<<dim3(16, 4), 256, 0, stream>>>(PREW, GCNW, Pb, Gt, flags);
    k_prepw<<<dim3(64, 3), 256, 0, stream>>>(Pb, Gt, Wt0, Wt1);
    k_prepb<<<2, 256, 0, stream>>>(PREB, Gt, GCNB, cvec, dvec, flags);

    int ggrid = (N + 127) / 128;
    int agrid = (N + 7) / 8;                      // 2 nodes/wave, 4 waves/block
    k_gemm1<<<ggrid, 512, 0, stream>>>(X, Xb, Wt0, cvec, dinv, U, N, flags);
    k_agg<<<agrid, 256, 0, stream>>>(U, rowptr, col, dinv, dvec, Y, N);
    k_gemm<<<ggrid, 512, 0, stream>>>(Xb, Y, Wt1, cvec + 256, dinv, U, N, 512);
    k_agg<<<agrid, 256, 0, stream>>>(U, rowptr, col, dinv, dvec + 256, Y, N);
    k_pool<<<(N + 63) / 64, 256, 0, stream>>>(Y, BATCH, N, psum, pkey, pcnt, flags);
    k_cls<<<64, 64, 0, stream>>>(psum, pkey, pcnt, CLSW, CLSB,
                                 (float*)d_out, (unsigned short*)d_out, flags);
}